// Round 11
// baseline (82.300 us; speedup 1.0000x reference)
//
#include <hip/hip_runtime.h>
#include <math.h>

#define C_FINE   100
#define C_MID    20
#define C_COARSE 5
#define D        128
#define NROWS    262144
#define NPAIRS   4950   // 100*99/2
#define NBLK4    78     // ceil(4950/64)

#define NB       256              // kMF blocks (1024 thr = 16 waves; 1 block/CU)
#define RPB      1024             // rows per block
#define NSTEP    8                // steps of 32 rows per row-group (256 rows / 32)
#define MT       7                // 112 padded classes / 16

// ws layout in floats
#define FP_OFF    0          // fine protos [100][128]
#define DM_OFF    12800      // mid dist table [20][20]
#define DC_OFF    13200      // coarse dist table [5][5]
#define ACC_OFF   13232      // 5 doubles (byte 52928, 8-aligned)
#define DONE_OFF  13244      // int completion counter
#define CNT_OFF   13248      // class counts [100] (float), padded to 128
#define FSUM_OFF  13376      // fine sums [100][128]
#define PART_OFF  26176      // partT [112 class][NB][128 dim]  (14.7 MB)
#define CNTT_OFF  3696192    // cntT [128 class][NB]

typedef __attribute__((ext_vector_type(8))) short bf16x8;   // 8 bf16 (4 VGPRs)
typedef __attribute__((ext_vector_type(4))) float f32x4;    // MFMA C/D

static __device__ __forceinline__ unsigned short f2bf(float f) {
    unsigned int x = __float_as_uint(f);
    x += 0x7FFF + ((x >> 16) & 1);      // round-to-nearest-even
    return (unsigned short)(x >> 16);
}

// ---------------- kMF: one-hot MFMA segment-sum, register-resident hot loop ----------------
// Verified fragment mapping (R8-R10, absmax 0.0):
//   A lane l: m-row = l&15 (+16*mt), k = 8*(l>>4)+j
//   B lane l: n-col = l&15 (+16n),   k = 8*(l>>4)+j
//   C/D lane l: col = l&15, row = 4*(l>>4)+i
// 16 waves: rg = wave>>2 owns rows [256rg,256rg+256); cw = wave&3 owns cols
// [32cw,32cw+32). NO barriers / NO LDS in the hot loop: B direct from global
// (named 2-deep reg dbuf), A built in regs from LDS-staged tgt (broadcast
// reads). End: rg-merge in LDS (one-time), transposed partial write.
__global__ __launch_bounds__(1024, 4) void kMF(const float* __restrict__ rep,
                                               const int* __restrict__ tgt,
                                               float* __restrict__ ws) {
    __shared__ int   ltgt[RPB];           // 4 KB
    __shared__ int   hist[128];
    __shared__ float slabs[4][112][33];   // 59 KB merge scratch (one-time)
    const int t  = threadIdx.x;
    const int wv = t >> 6;
    const int rg = wv >> 2;       // row-group 0..3
    const int cw = wv & 3;        // col-wave 0..3
    const int l  = t & 63;
    const int lg = l >> 4;        // k-group 0..3
    const int ll = l & 15;
    const int blk   = blockIdx.x;
    const int rbase = blk * RPB;

    if (t < 128) hist[t] = 0;
    __syncthreads();
    {
        int c = tgt[rbase + t];   // one row per thread
        ltgt[t] = c;
        atomicAdd(&hist[c], 1);
    }
    __syncthreads();              // ltgt + hist ready

    const int rowbase = rg * 256;               // within block
    const int colbase = 32 * cw + ll;

    f32x4 acc[MT][2];
    #pragma unroll
    for (int m = 0; m < MT; ++m)
        #pragma unroll
        for (int n = 0; n < 2; ++n)
            #pragma unroll
            for (int i = 0; i < 4; ++i) acc[m][n][i] = 0.f;

    float vA[16], vB[16];

#define LOADSTEP(V, s) do {                                                     \
    const float* p_ = rep + ((size_t)(rbase + rowbase + (s) * 32 + 8 * lg) * D  \
                             + colbase);                                        \
    _Pragma("unroll")                                                           \
    for (int j_ = 0; j_ < 8; ++j_) {                                            \
        V[j_]     = p_[j_ * D];                                                 \
        V[8 + j_] = p_[j_ * D + 16];                                            \
    }                                                                           \
} while (0)

#define COMPSTEP(V, s) do {                                                     \
    int tv_[8];                                                                 \
    _Pragma("unroll")                                                           \
    for (int j_ = 0; j_ < 8; ++j_)                                              \
        tv_[j_] = ltgt[rowbase + (s) * 32 + 8 * lg + j_];                       \
    bf16x8 b0_, b1_;                                                            \
    _Pragma("unroll")                                                           \
    for (int j_ = 0; j_ < 8; ++j_) {                                            \
        b0_[j_] = (short)f2bf(V[j_]);                                           \
        b1_[j_] = (short)f2bf(V[8 + j_]);                                       \
    }                                                                           \
    _Pragma("unroll")                                                           \
    for (int m_ = 0; m_ < MT; ++m_) {                                           \
        const int cb_ = 16 * m_ + ll;                                           \
        bf16x8 a_;                                                              \
        _Pragma("unroll")                                                       \
        for (int j_ = 0; j_ < 8; ++j_)                                          \
            a_[j_] = (tv_[j_] == cb_) ? (short)0x3F80 : (short)0;               \
        acc[m_][0] = __builtin_amdgcn_mfma_f32_16x16x32_bf16(a_, b0_, acc[m_][0], 0, 0, 0); \
        acc[m_][1] = __builtin_amdgcn_mfma_f32_16x16x32_bf16(a_, b1_, acc[m_][1], 0, 0, 0); \
    }                                                                           \
} while (0)

    LOADSTEP(vA, 0);
    #pragma unroll 1
    for (int s = 0; s < NSTEP; s += 2) {
        LOADSTEP(vB, s + 1);
        COMPSTEP(vA, s);
        if (s + 2 < NSTEP) LOADSTEP(vA, s + 2);
        COMPSTEP(vB, s + 1);
    }
#undef LOADSTEP
#undef COMPSTEP

    // ---- one-time merge of the 4 row-groups (sequential, 4 barriers) ----
    #pragma unroll 1
    for (int r = 0; r < 4; ++r) {
        if (rg == r) {
            #pragma unroll
            for (int m = 0; m < MT; ++m)
                #pragma unroll
                for (int n = 0; n < 2; ++n)
                    #pragma unroll
                    for (int i = 0; i < 4; ++i) {
                        const int cls = 16 * m + 4 * lg + i;
                        const int col = 16 * n + ll;
                        if (r == 0) slabs[cw][cls][col] = acc[m][n][i];
                        else        slabs[cw][cls][col] += acc[m][n][i];
                    }
        }
        __syncthreads();
    }

    // transposed partial write: partT[class][blk][dim] (kRed streams it)
    for (int e = t; e < 112 * 128; e += 1024) {
        const int c = e >> 7, d = e & 127;
        ws[PART_OFF + ((size_t)c * NB + blk) * 128 + d] = slabs[d >> 5][c][d & 31];
    }
    if (t < 128) ws[CNTT_OFF + t * NB + blk] = (float)hist[t];
}

// ---------------- kRed: coalesced merge of NB partials -> FSUM + CNT ----------------
__global__ __launch_bounds__(256) void kRed(float* __restrict__ ws) {
    const int c = blockIdx.x;            // class 0..99
    const int t = threadIdx.x;
    const int g = t >> 7, d = t & 127;
    const float* base = ws + PART_OFF + (size_t)c * NB * 128;
    float s = 0.f;
    #pragma unroll 8
    for (int b = g; b < NB; b += 2) s += base[b * 128 + d];
    __shared__ float red[2][128];
    red[g][d] = s;

    float cv = ws[CNTT_OFF + c * NB + t];   // t < 256 == NB
    #pragma unroll
    for (int off = 32; off > 0; off >>= 1) cv += __shfl_down(cv, off);
    __shared__ float cw[4];
    if ((t & 63) == 0) cw[t >> 6] = cv;
    __syncthreads();
    if (g == 0) ws[FSUM_OFF + c * D + d] = red[0][d] + red[1][d];
    if (t == 0) ws[CNT_OFF + c] = cw[0] + cw[1] + cw[2] + cw[3];
}

// ---------------- k3: normalize + hierarchy + distance tables (all in LDS) ----------------
__global__ __launch_bounds__(256) void k3_hier(const int* __restrict__ f2m,
                                               const int* __restrict__ f2c,
                                               float* __restrict__ ws) {
    __shared__ float fineP[C_FINE][D];        // 51.2 KB
    __shared__ float midP[C_MID][D + 1];
    __shared__ float coarP[C_COARSE][D + 1];
    __shared__ int   sf2m[C_FINE], sf2c[C_FINE], m2c[C_MID];
    __shared__ float midCnt[C_MID], coarCnt[C_COARSE];
    __shared__ float sTot[C_FINE];
    const int t = threadIdx.x;

    if (t < C_FINE) {
        sf2m[t] = f2m[t]; sf2c[t] = f2c[t];
        sTot[t] = ws[CNT_OFF + t];
    }
    for (int e = t; e < C_MID * (D + 1); e += 256) ((float*)midP)[e] = 0.f;
    for (int e = t; e < C_COARSE * (D + 1); e += 256) ((float*)coarP)[e] = 0.f;
    __syncthreads();

    for (int e = t; e < C_FINE * D; e += 256) {
        int c = e >> 7, d = e & 127;
        float v = ws[FSUM_OFF + e] / fmaxf(sTot[c], 1.f);
        fineP[c][d] = v;
        ws[FP_OFF + e] = v;
    }
    if (t < C_MID) {
        int cntv = 0, mx = -2147483647;
        for (int f = 0; f < C_FINE; ++f)
            if (sf2m[f] == t) { ++cntv; mx = max(mx, sf2c[f]); }
        midCnt[t] = (float)max(cntv, 1);
        m2c[t] = mx;
    }
    __syncthreads();

    if (t < D) {
        const int d = t;
        for (int f = 0; f < C_FINE; ++f)
            midP[sf2m[f]][d] += fineP[f][d];
        for (int m = 0; m < C_MID; ++m)
            midP[m][d] /= midCnt[m];
    }
    if (t >= 128 && t < 128 + C_COARSE) {
        int cc = t - 128, cntv = 0;
        for (int m = 0; m < C_MID; ++m) if (m2c[m] == cc) ++cntv;
        coarCnt[cc] = (float)max(cntv, 1);
    }
    __syncthreads();

    if (t < D) {
        const int d = t;
        for (int m = 0; m < C_MID; ++m)
            coarP[m2c[m]][d] += midP[m][d];
        for (int cc = 0; cc < C_COARSE; ++cc)
            coarP[cc][d] /= coarCnt[cc];
    }
    __syncthreads();

    for (int e = t; e < C_MID * C_MID; e += 256) {
        int m1 = e / C_MID, m2 = e % C_MID;
        float ss = 0.f;
        #pragma unroll 8
        for (int d = 0; d < D; ++d) {
            float df = midP[m1][d] - midP[m2][d];
            ss += df * df;
        }
        ws[DM_OFF + e] = sqrtf(ss + 1e-12f);
    }
    for (int e = t; e < C_COARSE * C_COARSE; e += 256) {
        int c1 = e / C_COARSE, c2 = e % C_COARSE;
        float ss = 0.f;
        #pragma unroll 8
        for (int d = 0; d < D; ++d) {
            float df = coarP[c1][d] - coarP[c2][d];
            ss += df * df;
        }
        ws[DC_OFF + e] = sqrtf(ss + 1e-12f);
    }
    if (t < 5) ((double*)(ws + ACC_OFF))[t] = 0.0;   // zero moment accumulators
    if (t == 5) ((int*)ws + DONE_OFF)[0] = 0;        // zero completion counter
}

// ---------------- k45: all fine pairs -> moments, last block finalizes ----------------
__global__ __launch_bounds__(64) void k45_pairs(float* __restrict__ ws,
                                                const int* __restrict__ f2m,
                                                const int* __restrict__ f2c,
                                                float* __restrict__ out) {
    const int p = blockIdx.x * 64 + threadIdx.x;
    double st = 0, sp = 0, stp = 0, stt = 0, spp = 0;
    if (p < NPAIRS) {
        int i = 0, rem = p;
        while (rem >= C_FINE - 1 - i) { rem -= C_FINE - 1 - i; ++i; }
        int j = i + 1 + rem;

        const float4* Fi = (const float4*)(ws + FP_OFF + i * D);
        const float4* Fj = (const float4*)(ws + FP_OFF + j * D);
        float ss = 0.f;
        #pragma unroll
        for (int k = 0; k < D / 4; ++k) {
            float4 a = Fi[k], b = Fj[k];
            float dx = a.x - b.x, dy = a.y - b.y, dz = a.z - b.z, dw = a.w - b.w;
            ss += dx * dx + dy * dy + dz * dz + dw * dw;
        }
        float proto = sqrtf(ss + 1e-12f);
        float tree  = ws[DC_OFF + f2c[i] * C_COARSE + f2c[j]]
                    + ws[DM_OFF + f2m[i] * C_MID + f2m[j]];
        st = tree; sp = proto;
        stp = (double)tree * (double)proto;
        stt = (double)tree * (double)tree;
        spp = (double)proto * (double)proto;
    }
    for (int off = 32; off > 0; off >>= 1) {
        st  += __shfl_down(st, off);
        sp  += __shfl_down(sp, off);
        stp += __shfl_down(stp, off);
        stt += __shfl_down(stt, off);
        spp += __shfl_down(spp, off);
    }
    if (threadIdx.x == 0) {
        double* acc = (double*)(ws + ACC_OFF);
        atomicAdd(&acc[0], st);
        atomicAdd(&acc[1], sp);
        atomicAdd(&acc[2], stp);
        atomicAdd(&acc[3], stt);
        atomicAdd(&acc[4], spp);
        __threadfence();
        int* done = (int*)ws + DONE_OFF;
        int ticket = atomicAdd(done, 1);
        if (ticket == NBLK4 - 1) {
            double fst  = atomicAdd(&acc[0], 0.0);
            double fsp  = atomicAdd(&acc[1], 0.0);
            double fstp = atomicAdd(&acc[2], 0.0);
            double fstt = atomicAdd(&acc[3], 0.0);
            double fspp = atomicAdd(&acc[4], 0.0);
            const double n = (double)NPAIRS;
            double num = fstp - fst * fsp / n;
            double dtt = fstt - fst * fst / n;
            double dpp = fspp - fsp * fsp / n;
            double corr = num / sqrt(dtt * dpp + 1e-12);
            out[0] = (float)(1.0 - corr);
        }
    }
}

extern "C" void kernel_launch(void* const* d_in, const int* in_sizes, int n_in,
                              void* d_out, int out_size, void* d_ws, size_t ws_size,
                              hipStream_t stream) {
    const float* rep = (const float*)d_in[0];
    const int*   tgt = (const int*)d_in[1];
    const int*   f2m = (const int*)d_in[2];
    const int*   f2c = (const int*)d_in[3];
    float* ws  = (float*)d_ws;
    float* out = (float*)d_out;

    hipLaunchKernelGGL(kMF,       dim3(NB),     dim3(1024), 0, stream, rep, tgt, ws);
    hipLaunchKernelGGL(kRed,      dim3(C_FINE), dim3(256),  0, stream, ws);
    hipLaunchKernelGGL(k3_hier,   dim3(1),      dim3(256),  0, stream, f2m, f2c, ws);
    hipLaunchKernelGGL(k45_pairs, dim3(NBLK4),  dim3(64),   0, stream,
                       ws, f2m, f2c, out);
}